// Round 2
// baseline (3063.483 us; speedup 1.0000x reference)
//
#include <hip/hip_runtime.h>
#include <hip/hip_bf16.h>

#define T_LEN 4096
#define H_DIM 2048
#define HKn 16
#define HVn 32
#define DKn 128
#define DVn 128
#define KEY_DIM 2048
#define VAL_DIM 4096
#define QKVZ_N 12288

typedef unsigned int u32;
typedef unsigned short u16;
typedef __attribute__((ext_vector_type(8))) short bf16x8;
typedef __attribute__((ext_vector_type(4))) float f32x4;

__device__ __forceinline__ u16 f2bf(float x){
  u32 u = __float_as_uint(x);
  u32 r = (u + 0x7fffu + ((u>>16)&1u)) >> 16;
  return (u16)r;
}
__device__ __forceinline__ float bf2f(u32 b){ return __uint_as_float(b<<16); }
__device__ __forceinline__ u32 packbf(float a, float b){ return (u32)f2bf(a) | ((u32)f2bf(b)<<16); }

// ---------------- fp32 -> bf16 elementwise ----------------
__global__ __launch_bounds__(256) void k_cvt(const float* __restrict__ in, u16* __restrict__ out, int n){
  int i = (blockIdx.x*256 + threadIdx.x)*8;
  if (i >= n) return;
  float4 a = *(const float4*)(in+i);
  float4 b = *(const float4*)(in+i+4);
  uint4 o;
  o.x = packbf(a.x,a.y); o.y = packbf(a.z,a.w);
  o.z = packbf(b.x,b.y); o.w = packbf(b.z,b.w);
  *(uint4*)(out+i) = o;
}

// ---------------- fp32 [R][C] -> bf16 transposed [C][R] ----------------
__global__ __launch_bounds__(256) void k_tcvt(const float* __restrict__ in, u16* __restrict__ out, int R, int C){
  __shared__ float tile[32][33];
  int c0 = blockIdx.x*32, r0 = blockIdx.y*32;
  int tx = threadIdx.x & 31, ty = threadIdx.x >> 5;
#pragma unroll
  for (int i=0;i<4;++i) tile[ty+8*i][tx] = in[(size_t)(r0+ty+8*i)*C + c0+tx];
  __syncthreads();
#pragma unroll
  for (int i=0;i<4;++i) out[(size_t)(c0+ty+8*i)*R + r0+tx] = f2bf(tile[tx][ty+8*i]);
}

// ---------------- ba = X @ W_ba  ->  g, beta ----------------
__global__ __launch_bounds__(256) void k_ba(const float* __restrict__ X, const float* __restrict__ W,
    const float* __restrict__ A_log, const float* __restrict__ dt_bias,
    float* __restrict__ g, float* __restrict__ beta){
  int tid = threadIdx.x;
  int t = blockIdx.x*4 + (tid>>6);
  int j = tid & 63;
  const float* xr = X + (size_t)t*H_DIM;
  float acc = 0.f;
  for (int k=0;k<H_DIM;k+=4){
    float4 xv = *(const float4*)(xr+k);
    acc += xv.x*W[(size_t)(k+0)*64 + j];
    acc += xv.y*W[(size_t)(k+1)*64 + j];
    acc += xv.z*W[(size_t)(k+2)*64 + j];
    acc += xv.w*W[(size_t)(k+3)*64 + j];
  }
  if (j < HVn) {
    beta[t*HVn + j] = 1.f/(1.f+__expf(-acc));
  } else {
    int h = j - HVn;
    float x = acc + dt_bias[h];
    float sp = (x > 20.f) ? x : log1pf(__expf(x));
    g[t*HVn + h] = -__expf(A_log[h]) * sp;
  }
}

// ---------------- bf16 MFMA GEMM: C[M][N] = A[M][K] * BT[N][K]^T ----------------
typedef const __attribute__((address_space(1))) u32* gas_t;
typedef __attribute__((address_space(3))) u32* las_t;
__device__ __forceinline__ void gld16(const void* g, void* l){
  __builtin_amdgcn_global_load_lds((gas_t)g, (las_t)l, 16, 0, 0);
}

template<int WRITE_BF16>
__global__ __launch_bounds__(256) void k_gemm(const u16* __restrict__ A, const u16* __restrict__ BT,
                                              void* __restrict__ Cout, int M, int N, int K){
  __shared__ __align__(16) u16 As[128*32];
  __shared__ __align__(16) u16 Bs[128*32];
  int tid = threadIdx.x, lane = tid & 63, wave = tid >> 6;
  int wr = wave >> 1, wc = wave & 1;
  int m0 = blockIdx.x*128, n0 = blockIdx.y*128;
  int fr = lane & 15, fq = lane >> 4;
  f32x4 zero = {0.f,0.f,0.f,0.f};
  f32x4 acc[4][4];
#pragma unroll
  for (int m=0;m<4;++m)
#pragma unroll
    for (int n=0;n<4;++n) acc[m][n] = zero;

  for (int kt=0; kt<K; kt+=32){
#pragma unroll
    for (int it=0; it<2; ++it){
      int c = (it*4 + wave)*64 + lane;      // 0..511 chunk of 16B
      int row = c >> 2, kc = (c & 3) << 3;
      gld16(A  + (size_t)(m0+row)*K + kt + kc, (char*)As + (size_t)(it*4+wave)*1024);
      gld16(BT + (size_t)(n0+row)*K + kt + kc, (char*)Bs + (size_t)(it*4+wave)*1024);
    }
    __syncthreads();
    bf16x8 af[4], bff[4];
#pragma unroll
    for (int m=0;m<4;++m) af[m]  = *(const bf16x8*)(As + (wr*64 + m*16 + fr)*32 + fq*8);
#pragma unroll
    for (int n=0;n<4;++n) bff[n] = *(const bf16x8*)(Bs + (wc*64 + n*16 + fr)*32 + fq*8);
#pragma unroll
    for (int m=0;m<4;++m)
#pragma unroll
      for (int n=0;n<4;++n)
        acc[m][n] = __builtin_amdgcn_mfma_f32_16x16x32_bf16(af[m], bff[n], acc[m][n], 0,0,0);
    __syncthreads();
  }
#pragma unroll
  for (int m=0;m<4;++m)
#pragma unroll
    for (int n=0;n<4;++n){
      int row = m0 + wr*64 + m*16 + fq*4;
      int col = n0 + wc*64 + n*16 + fr;
#pragma unroll
      for (int r=0;r<4;++r){
        float v = acc[m][n][r];
        if (WRITE_BF16) ((u16*)Cout)[(size_t)(row+r)*N + col] = f2bf(v);
        else            ((float*)Cout)[(size_t)(row+r)*N + col] = v;
      }
    }
}

// ---------------- causal depthwise conv(KW=4) + SiLU + l2norm(q,k) -> bf16 ----------------
__global__ __launch_bounds__(256) void k_conv(const u16* __restrict__ qkvz, const float* __restrict__ cw,
    u16* __restrict__ qn, u16* __restrict__ kn, u16* __restrict__ vv){
  int t = blockIdx.x;
  int region = blockIdx.y;                 // 0:q 1:k 2,3:v
  int c = region*2048 + threadIdx.x*8;     // 8 channels per thread
  float wgt[8][4];
#pragma unroll
  for (int i=0;i<8;++i){
    float4 wv = *(const float4*)(cw + (size_t)(c+i)*4);
    wgt[i][0]=wv.x; wgt[i][1]=wv.y; wgt[i][2]=wv.z; wgt[i][3]=wv.w;
  }
  float y[8];
#pragma unroll
  for (int i=0;i<8;++i) y[i]=0.f;
#pragma unroll
  for (int j=0;j<4;++j){
    int tt = t + j - 3;
    if (tt < 0) continue;
    uint4 raw = *(const uint4*)(qkvz + (size_t)tt*QKVZ_N + c);
    float xv[8];
    xv[0]=bf2f(raw.x&0xffffu); xv[1]=bf2f(raw.x>>16);
    xv[2]=bf2f(raw.y&0xffffu); xv[3]=bf2f(raw.y>>16);
    xv[4]=bf2f(raw.z&0xffffu); xv[5]=bf2f(raw.z>>16);
    xv[6]=bf2f(raw.w&0xffffu); xv[7]=bf2f(raw.w>>16);
#pragma unroll
    for (int i=0;i<8;++i) y[i] += xv[i]*wgt[i][j];
  }
#pragma unroll
  for (int i=0;i<8;++i){ y[i] = y[i] / (1.f + __expf(-y[i])); }   // SiLU

  if (region <= 1){
    float ss = 0.f;
#pragma unroll
    for (int i=0;i<8;++i) ss += y[i]*y[i];
    ss += __shfl_xor(ss,1); ss += __shfl_xor(ss,2);
    ss += __shfl_xor(ss,4); ss += __shfl_xor(ss,8);   // 16 lanes = one 128-dim head
    float sc = 1.f/sqrtf(ss + 1e-6f);
    if (region==0) sc *= 0.08838834764831845f;        // DK^-0.5
#pragma unroll
    for (int i=0;i<8;++i) y[i]*=sc;
    u16* dst = (region==0 ? qn : kn) + (size_t)t*KEY_DIM + (c - region*2048);
    *(uint4*)dst = make_uint4(packbf(y[0],y[1]),packbf(y[2],y[3]),packbf(y[4],y[5]),packbf(y[6],y[7]));
  } else {
    u16* dst = vv + (size_t)t*VAL_DIM + (c - 4096);
    *(uint4*)dst = make_uint4(packbf(y[0],y[1]),packbf(y[2],y[3]),packbf(y[4],y[5]),packbf(y[6],y[7]));
  }
}

// ---------------- gated delta rule recurrence ----------------
// 4096 independent state columns (h, v). 2 columns per wave: 32 lanes x 4 d-elems.
__global__ __launch_bounds__(256) void k_recur(const u16* __restrict__ qn, const u16* __restrict__ kn,
   const u16* __restrict__ vv, const float* __restrict__ g, const float* __restrict__ beta,
   float* __restrict__ o){
  int lane = threadIdx.x & 63, wave = threadIdx.x >> 6;
  int gw = blockIdx.x*4 + wave;            // 0..2047
  int h = gw >> 6;                         // 32 heads, 64 waves/head
  int vcol = ((gw & 63) << 1) | (lane >> 5);
  int kh = h >> 1;                         // GQA repeat r=2
  int dl = (lane & 31) << 2;               // 4 d-elems per lane
  const u16* kp = kn + kh*DKn + dl;
  const u16* qp = qn + kh*DKn + dl;
  const u16* vp = vv + h*DVn + vcol;
  const float* gp = g + h;
  const float* bp = beta + h;
  float* op = o + h*DVn + vcol;
  ushort4 kf = *(const ushort4*)kp;
  ushort4 qf = *(const ushort4*)qp;
  u16 vt = *vp; float gt = *gp, bt = *bp;
  float S0=0.f,S1=0.f,S2=0.f,S3=0.f;
  for (int t=0; t<T_LEN; ++t){
    ushort4 kc=kf, qc=qf; u16 vc=vt; float gc=gt, bc=bt;
    int tn = (t+1 < T_LEN) ? t+1 : t;      // prefetch next step
    kf = *(const ushort4*)(kp + (size_t)tn*KEY_DIM);
    qf = *(const ushort4*)(qp + (size_t)tn*KEY_DIM);
    vt = vp[(size_t)tn*VAL_DIM];
    gt = gp[(size_t)tn*HVn];
    bt = bp[(size_t)tn*HVn];
    float k0=bf2f(kc.x), k1=bf2f(kc.y), k2=bf2f(kc.z), k3=bf2f(kc.w);
    float eg = __expf(gc);
    float kv = k0*S0 + k1*S1 + k2*S2 + k3*S3;
    kv += __shfl_xor(kv,1);  kv += __shfl_xor(kv,2);  kv += __shfl_xor(kv,4);
    kv += __shfl_xor(kv,8);  kv += __shfl_xor(kv,16);
    float delta = (bf2f(vc) - eg*kv)*bc;
    S0 = eg*S0 + k0*delta; S1 = eg*S1 + k1*delta;
    S2 = eg*S2 + k2*delta; S3 = eg*S3 + k3*delta;
    float ov = bf2f(qc.x)*S0 + bf2f(qc.y)*S1 + bf2f(qc.z)*S2 + bf2f(qc.w)*S3;
    ov += __shfl_xor(ov,1);  ov += __shfl_xor(ov,2);  ov += __shfl_xor(ov,4);
    ov += __shfl_xor(ov,8);  ov += __shfl_xor(ov,16);
    if ((lane & 31) == 0) op[(size_t)t*VAL_DIM] = ov;
  }
}

// ---------------- gated RMSNorm * silu(z) -> bf16 ----------------
__global__ __launch_bounds__(256) void k_gnorm(const float* __restrict__ o, const u16* __restrict__ qkvz,
    const float* __restrict__ nw, u16* __restrict__ og){
  int t = blockIdx.x;
  int base = threadIdx.x*16;               // 16 elems/thread, 8 threads per 128-dim head
  const float* src = o + (size_t)t*VAL_DIM + base;
  float x[16];
#pragma unroll
  for (int i=0;i<4;++i){
    float4 f = *(const float4*)(src + i*4);
    x[i*4+0]=f.x; x[i*4+1]=f.y; x[i*4+2]=f.z; x[i*4+3]=f.w;
  }
  float ss=0.f;
#pragma unroll
  for (int i=0;i<16;++i) ss += x[i]*x[i];
  ss += __shfl_xor(ss,1); ss += __shfl_xor(ss,2); ss += __shfl_xor(ss,4);
  float rs = 1.f/sqrtf(ss*(1.f/128.f) + 1e-6f);
  const u16* zp = qkvz + (size_t)t*QKVZ_N + 8192 + base;
  uint4 z0 = *(const uint4*)zp;
  uint4 z1 = *(const uint4*)(zp+8);
  u32 zr[8] = {z0.x,z0.y,z0.z,z0.w,z1.x,z1.y,z1.z,z1.w};
  u32 outw[8];
#pragma unroll
  for (int p=0;p<8;++p){
    float za = bf2f(zr[p]&0xffffu), zb = bf2f(zr[p]>>16);
    float sa = za/(1.f+__expf(-za)), sb = zb/(1.f+__expf(-zb));
    int i0 = p*2, i1 = p*2+1;
    float oa = x[i0]*rs*nw[(base+i0)&127]*sa;
    float ob = x[i1]*rs*nw[(base+i1)&127]*sb;
    outw[p] = packbf(oa, ob);
  }
  uint4* dst = (uint4*)(og + (size_t)t*VAL_DIM + base);
  dst[0] = make_uint4(outw[0],outw[1],outw[2],outw[3]);
  dst[1] = make_uint4(outw[4],outw[5],outw[6],outw[7]);
}

extern "C" void kernel_launch(void* const* d_in, const int* in_sizes, int n_in,
                              void* d_out, int out_size, void* d_ws, size_t ws_size,
                              hipStream_t stream) {
  const float* hidden  = (const float*)d_in[0];
  const float* W_qkvz  = (const float*)d_in[1];
  const float* W_ba    = (const float*)d_in[2];
  const float* conv_w  = (const float*)d_in[3];
  const float* A_log   = (const float*)d_in[4];
  const float* dt_bias = (const float*)d_in[5];
  const float* norm_w  = (const float*)d_in[6];
  const float* W_out   = (const float*)d_in[7];

  // workspace layout (253MB, with write-before-read aliasing):
  //   [0, 16.8M)      Xb   (bf16 hidden)        } aliased by O (fp32, 67.1M)
  //   [16.8M, 67.1M)  W1T  (bf16 W_qkvz^T)      }  after GEMM1
  //   [67.1M, 167.8M) QKVZ (bf16)
  //   [167.8M,184.5M) QN   (bf16)               } aliased by OG (bf16, 33.6M)
  //   [184.5M,201.3M) KN   (bf16)               }  after recurrence
  //   [201.3M,234.9M) V    (bf16)
  //   [234.9M,251.7M) WoT  (bf16 W_out^T)
  //   [251.7M,252.7M) G, B (fp32)
  char* w = (char*)d_ws;
  size_t need = 252706816;
  if (ws_size < need) return;   // signals clean absmax failure instead of OOB crash

  u16*   Xb   = (u16*)(w + 0);
  u16*   W1T  = (u16*)(w + 16777216);
  u16*   QKVZ = (u16*)(w + 67108864);
  u16*   QN   = (u16*)(w + 167772160);
  u16*   KN   = (u16*)(w + 184549376);
  u16*   V    = (u16*)(w + 201326592);
  u16*   WoT  = (u16*)(w + 234881024);
  float* G    = (float*)(w + 251658240);
  float* B    = (float*)(w + 252182528);
  float* O    = (float*)(w + 0);           // alias Xb+W1T (dead after GEMM1)
  u16*   OG   = (u16*)(w + 167772160);     // alias QN+KN (dead after recurrence)

  k_cvt<<<4096,256,0,stream>>>(hidden, Xb, T_LEN*H_DIM);
  k_tcvt<<<dim3(QKVZ_N/32, H_DIM/32),256,0,stream>>>(W_qkvz, W1T, H_DIM, QKVZ_N);
  k_tcvt<<<dim3(H_DIM/32, VAL_DIM/32),256,0,stream>>>(W_out, WoT, VAL_DIM, H_DIM);
  k_ba<<<T_LEN/4,256,0,stream>>>(hidden, W_ba, A_log, dt_bias, G, B);
  k_gemm<1><<<dim3(T_LEN/128, QKVZ_N/128),256,0,stream>>>(Xb, W1T, QKVZ, T_LEN, QKVZ_N, H_DIM);
  k_conv<<<dim3(T_LEN,4),256,0,stream>>>(QKVZ, conv_w, QN, KN, V);
  k_recur<<<512,256,0,stream>>>(QN, KN, V, G, B, O);
  k_gnorm<<<T_LEN,256,0,stream>>>(O, QKVZ, norm_w, OG);
  k_gemm<0><<<dim3(T_LEN/128, H_DIM/128),256,0,stream>>>(OG, WoT, d_out, T_LEN, H_DIM, VAL_DIM);
}

// Round 4
// 2653.136 us; speedup vs baseline: 1.1547x; 1.1547x over previous
//
#include <hip/hip_runtime.h>
#include <hip/hip_bf16.h>

#define T_LEN 4096
#define H_DIM 2048
#define HKn 16
#define HVn 32
#define DKn 128
#define DVn 128
#define KEY_DIM 2048
#define VAL_DIM 4096
#define QKVZ_N 12288

typedef unsigned int u32;
typedef unsigned short u16;
typedef __attribute__((ext_vector_type(8))) short bf16x8;
typedef __attribute__((ext_vector_type(4))) float f32x4;

__device__ __forceinline__ u16 f2bf(float x){
  u32 u = __float_as_uint(x);
  u32 r = (u + 0x7fffu + ((u>>16)&1u)) >> 16;
  return (u16)r;
}
__device__ __forceinline__ float bf2f(u32 b){ return __uint_as_float(b<<16); }
__device__ __forceinline__ u32 packbf(float a, float b){ return (u32)f2bf(a) | ((u32)f2bf(b)<<16); }

// DPP-accumulate reduction within 32-lane halves: result broadcast to all lanes.
template<int CTRL>
__device__ __forceinline__ float dpp_add(float x){
  int y = __builtin_amdgcn_update_dpp(0, __float_as_int(x), CTRL, 0xF, 0xF, true);
  return x + __int_as_float(y);
}
__device__ __forceinline__ float red32(float x){
  x = dpp_add<0xB1>(x);   // quad_perm [1,0,3,2]  (xor 1)
  x = dpp_add<0x4E>(x);   // quad_perm [2,3,0,1]  (xor 2)
  x = dpp_add<0x124>(x);  // row_ror:4
  x = dpp_add<0x128>(x);  // row_ror:8  -> every lane of 16-row has 16-sum
  int s = __builtin_amdgcn_ds_swizzle(__float_as_int(x), 0x401F); // xor 16 (within 32)
  return x + __int_as_float(s);
}

// ---------------- fp32 -> bf16 elementwise ----------------
__global__ __launch_bounds__(256) void k_cvt(const float* __restrict__ in, u16* __restrict__ out, int n){
  int i = (blockIdx.x*256 + threadIdx.x)*8;
  if (i >= n) return;
  float4 a = *(const float4*)(in+i);
  float4 b = *(const float4*)(in+i+4);
  uint4 o;
  o.x = packbf(a.x,a.y); o.y = packbf(a.z,a.w);
  o.z = packbf(b.x,b.y); o.w = packbf(b.z,b.w);
  *(uint4*)(out+i) = o;
}

// ---------------- fp32 [R][C] -> bf16 transposed [C][R] ----------------
__global__ __launch_bounds__(256) void k_tcvt(const float* __restrict__ in, u16* __restrict__ out, int R, int C){
  __shared__ float tile[32][33];
  int c0 = blockIdx.x*32, r0 = blockIdx.y*32;
  int tx = threadIdx.x & 31, ty = threadIdx.x >> 5;
#pragma unroll
  for (int i=0;i<4;++i) tile[ty+8*i][tx] = in[(size_t)(r0+ty+8*i)*C + c0+tx];
  __syncthreads();
#pragma unroll
  for (int i=0;i<4;++i) out[(size_t)(c0+ty+8*i)*R + r0+tx] = f2bf(tile[tx][ty+8*i]);
}

// ---------------- ba = X @ W_ba  ->  eg = exp(g), beta ----------------
__global__ __launch_bounds__(256) void k_ba(const float* __restrict__ X, const float* __restrict__ W,
    const float* __restrict__ A_log, const float* __restrict__ dt_bias,
    float* __restrict__ eg, float* __restrict__ beta){
  int tid = threadIdx.x;
  int t = blockIdx.x*4 + (tid>>6);
  int j = tid & 63;
  const float* xr = X + (size_t)t*H_DIM;
  float acc = 0.f;
  for (int k=0;k<H_DIM;k+=4){
    float4 xv = *(const float4*)(xr+k);
    acc += xv.x*W[(size_t)(k+0)*64 + j];
    acc += xv.y*W[(size_t)(k+1)*64 + j];
    acc += xv.z*W[(size_t)(k+2)*64 + j];
    acc += xv.w*W[(size_t)(k+3)*64 + j];
  }
  if (j < HVn) {
    beta[t*HVn + j] = 1.f/(1.f+__expf(-acc));
  } else {
    int h = j - HVn;
    float x = acc + dt_bias[h];
    float sp = (x > 20.f) ? x : log1pf(__expf(x));
    eg[t*HVn + h] = __expf(-__expf(A_log[h]) * sp);   // exp(g) precomputed
  }
}

// ---------------- bf16 MFMA GEMM: C[M][N] = A[M][K] * BT[N][K]^T ----------------
typedef const __attribute__((address_space(1))) u32* gas_t;
typedef __attribute__((address_space(3))) u32* las_t;
__device__ __forceinline__ void gld16(const void* g, void* l){
  __builtin_amdgcn_global_load_lds((gas_t)g, (las_t)l, 16, 0, 0);
}

template<int WRITE_BF16>
__global__ __launch_bounds__(256) void k_gemm(const u16* __restrict__ A, const u16* __restrict__ BT,
                                              void* __restrict__ Cout, int M, int N, int K){
  __shared__ __align__(16) u16 As[128*32];
  __shared__ __align__(16) u16 Bs[128*32];
  int tid = threadIdx.x, lane = tid & 63, wave = tid >> 6;
  int wr = wave >> 1, wc = wave & 1;
  int m0 = blockIdx.x*128, n0 = blockIdx.y*128;
  int fr = lane & 15, fq = lane >> 4;
  f32x4 zero = {0.f,0.f,0.f,0.f};
  f32x4 acc[4][4];
#pragma unroll
  for (int m=0;m<4;++m)
#pragma unroll
    for (int n=0;n<4;++n) acc[m][n] = zero;

  for (int kt=0; kt<K; kt+=32){
#pragma unroll
    for (int it=0; it<2; ++it){
      int c = (it*4 + wave)*64 + lane;      // 0..511 chunk of 16B
      int row = c >> 2, kc = (c & 3) << 3;
      gld16(A  + (size_t)(m0+row)*K + kt + kc, (char*)As + (size_t)(it*4+wave)*1024);
      gld16(BT + (size_t)(n0+row)*K + kt + kc, (char*)Bs + (size_t)(it*4+wave)*1024);
    }
    __syncthreads();
    bf16x8 af[4], bff[4];
#pragma unroll
    for (int m=0;m<4;++m) af[m]  = *(const bf16x8*)(As + (wr*64 + m*16 + fr)*32 + fq*8);
#pragma unroll
    for (int n=0;n<4;++n) bff[n] = *(const bf16x8*)(Bs + (wc*64 + n*16 + fr)*32 + fq*8);
#pragma unroll
    for (int m=0;m<4;++m)
#pragma unroll
      for (int n=0;n<4;++n)
        acc[m][n] = __builtin_amdgcn_mfma_f32_16x16x32_bf16(af[m], bff[n], acc[m][n], 0,0,0);
    __syncthreads();
  }
#pragma unroll
  for (int m=0;m<4;++m)
#pragma unroll
    for (int n=0;n<4;++n){
      int row = m0 + wr*64 + m*16 + fq*4;
      int col = n0 + wc*64 + n*16 + fr;
#pragma unroll
      for (int r=0;r<4;++r){
        float v = acc[m][n][r];
        if (WRITE_BF16) ((u16*)Cout)[(size_t)(row+r)*N + col] = f2bf(v);
        else            ((float*)Cout)[(size_t)(row+r)*N + col] = v;
      }
    }
}

// ---------------- causal depthwise conv(KW=4) + SiLU + l2norm(q,k) -> bf16 ----------------
__global__ __launch_bounds__(256) void k_conv(const u16* __restrict__ qkvz, const float* __restrict__ cw,
    u16* __restrict__ qn, u16* __restrict__ kn, u16* __restrict__ vv){
  int t = blockIdx.x;
  int region = blockIdx.y;                 // 0:q 1:k 2,3:v
  int c = region*2048 + threadIdx.x*8;     // 8 channels per thread
  float wgt[8][4];
#pragma unroll
  for (int i=0;i<8;++i){
    float4 wv = *(const float4*)(cw + (size_t)(c+i)*4);
    wgt[i][0]=wv.x; wgt[i][1]=wv.y; wgt[i][2]=wv.z; wgt[i][3]=wv.w;
  }
  float y[8];
#pragma unroll
  for (int i=0;i<8;++i) y[i]=0.f;
#pragma unroll
  for (int j=0;j<4;++j){
    int tt = t + j - 3;
    if (tt < 0) continue;
    uint4 raw = *(const uint4*)(qkvz + (size_t)tt*QKVZ_N + c);
    float xv[8];
    xv[0]=bf2f(raw.x&0xffffu); xv[1]=bf2f(raw.x>>16);
    xv[2]=bf2f(raw.y&0xffffu); xv[3]=bf2f(raw.y>>16);
    xv[4]=bf2f(raw.z&0xffffu); xv[5]=bf2f(raw.z>>16);
    xv[6]=bf2f(raw.w&0xffffu); xv[7]=bf2f(raw.w>>16);
#pragma unroll
    for (int i=0;i<8;++i) y[i] += xv[i]*wgt[i][j];
  }
#pragma unroll
  for (int i=0;i<8;++i){ y[i] = y[i] / (1.f + __expf(-y[i])); }   // SiLU

  if (region <= 1){
    float ss = 0.f;
#pragma unroll
    for (int i=0;i<8;++i) ss += y[i]*y[i];
    ss += __shfl_xor(ss,1); ss += __shfl_xor(ss,2);
    ss += __shfl_xor(ss,4); ss += __shfl_xor(ss,8);   // 16 lanes = one 128-dim head
    float sc = 1.f/sqrtf(ss + 1e-6f);
    if (region==0) sc *= 0.08838834764831845f;        // DK^-0.5
#pragma unroll
    for (int i=0;i<8;++i) y[i]*=sc;
    u16* dst = (region==0 ? qn : kn) + (size_t)t*KEY_DIM + (c - region*2048);
    *(uint4*)dst = make_uint4(packbf(y[0],y[1]),packbf(y[2],y[3]),packbf(y[4],y[5]),packbf(y[6],y[7]));
  } else {
    u16* dst = vv + (size_t)t*VAL_DIM + (c - 4096);
    *(uint4*)dst = make_uint4(packbf(y[0],y[1]),packbf(y[2],y[3]),packbf(y[4],y[5]),packbf(y[6],y[7]));
  }
}

// ---------------- gated delta rule recurrence ----------------
// 4096 independent state columns (h, v). 2 columns per wave: 32 lanes x 4 d-elems.
// DPP-based reductions, 32-bit incrementing offsets, exp(g) precomputed.
__global__ __launch_bounds__(256) void k_recur(const u16* __restrict__ qn, const u16* __restrict__ kn,
   const u16* __restrict__ vv, const float* __restrict__ eg_arr, const float* __restrict__ beta,
   float* __restrict__ o){
  int lane = threadIdx.x & 63, wave = threadIdx.x >> 6;
  int gw = blockIdx.x*4 + wave;            // 0..2047
  int h = gw >> 6;                         // 32 heads, 64 waves/head
  int vcol = ((gw & 63) << 1) | (lane >> 5);
  int kh = h >> 1;                         // GQA repeat r=2
  int dl = (lane & 31) << 2;               // 4 d-elems per lane

  const uint2* kp = (const uint2*)(kn + kh*DKn + dl);   // 8B-aligned
  const uint2* qp = (const uint2*)(qn + kh*DKn + dl);
  const u16*   vp = vv + h*DVn + vcol;
  const float* ep = eg_arr + h;
  const float* bp = beta + h;
  float*       op = o + h*DVn + vcol;

  int ko = 0, vo = 0, go = 0, oo = 0;      // 32-bit element offsets
  uint2 kf = kp[0], qf = qp[0];
  u16 vt_ = vp[0];
  float egf = ep[0], btf = bp[0];
  float S0=0.f,S1=0.f,S2=0.f,S3=0.f;
  bool writer = ((lane & 31) == 0);

  for (int t=0; t<T_LEN; ++t){
    uint2 kc=kf, qc=qf; u32 vc=vt_; float eg=egf, bc=btf;
    int adv = (t < T_LEN-1) ? 1 : 0;       // scalar select; last iter reloads row T-1
    ko += adv*(KEY_DIM/4);                 // uint2 units
    vo += adv*VAL_DIM;
    go += adv*HVn;
    kf = kp[ko]; qf = qp[ko];
    vt_ = vp[vo];
    egf = ep[go]; btf = bp[go];

    float k0 = __uint_as_float(kc.x << 16);
    float k1 = __uint_as_float(kc.x & 0xffff0000u);
    float k2 = __uint_as_float(kc.y << 16);
    float k3 = __uint_as_float(kc.y & 0xffff0000u);

    float kv = k0*S0 + k1*S1 + k2*S2 + k3*S3;
    kv = red32(kv);
    float delta = (bf2f(vc) - eg*kv)*bc;
    S0 = fmaf(k0, delta, eg*S0);
    S1 = fmaf(k1, delta, eg*S1);
    S2 = fmaf(k2, delta, eg*S2);
    S3 = fmaf(k3, delta, eg*S3);

    float q0 = __uint_as_float(qc.x << 16);
    float q1 = __uint_as_float(qc.x & 0xffff0000u);
    float q2 = __uint_as_float(qc.y << 16);
    float q3 = __uint_as_float(qc.y & 0xffff0000u);
    float ov = q0*S0 + q1*S1 + q2*S2 + q3*S3;
    ov = red32(ov);
    if (writer) op[oo] = ov;
    oo += VAL_DIM;
  }
}

// ---------------- gated RMSNorm * silu(z) -> bf16 ----------------
__global__ __launch_bounds__(256) void k_gnorm(const float* __restrict__ o, const u16* __restrict__ qkvz,
    const float* __restrict__ nw, u16* __restrict__ og){
  int t = blockIdx.x;
  int base = threadIdx.x*16;               // 16 elems/thread, 8 threads per 128-dim head
  const float* src = o + (size_t)t*VAL_DIM + base;
  float x[16];
#pragma unroll
  for (int i=0;i<4;++i){
    float4 f = *(const float4*)(src + i*4);
    x[i*4+0]=f.x; x[i*4+1]=f.y; x[i*4+2]=f.z; x[i*4+3]=f.w;
  }
  float ss=0.f;
#pragma unroll
  for (int i=0;i<16;++i) ss += x[i]*x[i];
  ss += __shfl_xor(ss,1); ss += __shfl_xor(ss,2); ss += __shfl_xor(ss,4);
  float rs = 1.f/sqrtf(ss*(1.f/128.f) + 1e-6f);
  const u16* zp = qkvz + (size_t)t*QKVZ_N + 8192 + base;
  uint4 z0 = *(const uint4*)zp;
  uint4 z1 = *(const uint4*)(zp+8);
  u32 zr[8] = {z0.x,z0.y,z0.z,z0.w,z1.x,z1.y,z1.z,z1.w};
  u32 outw[8];
#pragma unroll
  for (int p=0;p<8;++p){
    float za = bf2f(zr[p]&0xffffu), zb = bf2f(zr[p]>>16);
    float sa = za/(1.f+__expf(-za)), sb = zb/(1.f+__expf(-zb));
    int i0 = p*2, i1 = p*2+1;
    float oa = x[i0]*rs*nw[(base+i0)&127]*sa;
    float ob = x[i1]*rs*nw[(base+i1)&127]*sb;
    outw[p] = packbf(oa, ob);
  }
  uint4* dst = (uint4*)(og + (size_t)t*VAL_DIM + base);
  dst[0] = make_uint4(outw[0],outw[1],outw[2],outw[3]);
  dst[1] = make_uint4(outw[4],outw[5],outw[6],outw[7]);
}

extern "C" void kernel_launch(void* const* d_in, const int* in_sizes, int n_in,
                              void* d_out, int out_size, void* d_ws, size_t ws_size,
                              hipStream_t stream) {
  const float* hidden  = (const float*)d_in[0];
  const float* W_qkvz  = (const float*)d_in[1];
  const float* W_ba    = (const float*)d_in[2];
  const float* conv_w  = (const float*)d_in[3];
  const float* A_log   = (const float*)d_in[4];
  const float* dt_bias = (const float*)d_in[5];
  const float* norm_w  = (const float*)d_in[6];
  const float* W_out   = (const float*)d_in[7];

  // workspace layout (253MB, with write-before-read aliasing):
  //   [0, 16.8M)      Xb   (bf16 hidden)        } aliased by O (fp32, 67.1M)
  //   [16.8M, 67.1M)  W1T  (bf16 W_qkvz^T)      }  after GEMM1
  //   [67.1M, 167.8M) QKVZ (bf16)
  //   [167.8M,184.5M) QN   (bf16)               } aliased by OG (bf16, 33.6M)
  //   [184.5M,201.3M) KN   (bf16)               }  after recurrence
  //   [201.3M,234.9M) V    (bf16)
  //   [234.9M,251.7M) WoT  (bf16 W_out^T)
  //   [251.7M,252.7M) EG, B (fp32)
  char* w = (char*)d_ws;
  size_t need = 252706816;
  if (ws_size < need) return;

  u16*   Xb   = (u16*)(w + 0);
  u16*   W1T  = (u16*)(w + 16777216);
  u16*   QKVZ = (u16*)(w + 67108864);
  u16*   QN   = (u16*)(w + 167772160);
  u16*   KN   = (u16*)(w + 184549376);
  u16*   V    = (u16*)(w + 201326592);
  u16*   WoT  = (u16*)(w + 234881024);
  float* EG   = (float*)(w + 251658240);
  float* B    = (float*)(w + 252182528);
  float* O    = (float*)(w + 0);           // alias Xb+W1T (dead after GEMM1)
  u16*   OG   = (u16*)(w + 167772160);     // alias QN+KN (dead after recurrence)

  k_cvt<<<4096,256,0,stream>>>(hidden, Xb, T_LEN*H_DIM);
  k_tcvt<<<dim3(QKVZ_N/32, H_DIM/32),256,0,stream>>>(W_qkvz, W1T, H_DIM, QKVZ_N);
  k_tcvt<<<dim3(H_DIM/32, VAL_DIM/32),256,0,stream>>>(W_out, WoT, VAL_DIM, H_DIM);
  k_ba<<<T_LEN/4,256,0,stream>>>(hidden, W_ba, A_log, dt_bias, EG, B);
  k_gemm<1><<<dim3(T_LEN/128, QKVZ_N/128),256,0,stream>>>(Xb, W1T, QKVZ, T_LEN, QKVZ_N, H_DIM);
  k_conv<<<dim3(T_LEN,4),256,0,stream>>>(QKVZ, conv_w, QN, KN, V);
  k_recur<<<512,256,0,stream>>>(QN, KN, V, EG, B, O);
  k_gnorm<<<T_LEN,256,0,stream>>>(O, QKVZ, norm_w, OG);
  k_gemm<0><<<dim3(T_LEN/128, H_DIM/128),256,0,stream>>>(OG, WoT, d_out, T_LEN, H_DIM, VAL_DIM);
}

// Round 5
// 2306.610 us; speedup vs baseline: 1.3281x; 1.1502x over previous
//
#include <hip/hip_runtime.h>
#include <hip/hip_bf16.h>

#define T_LEN 4096
#define H_DIM 2048
#define HKn 16
#define HVn 32
#define DKn 128
#define DVn 128
#define KEY_DIM 2048
#define VAL_DIM 4096
#define QKVZ_N 12288

typedef unsigned int u32;
typedef unsigned short u16;
typedef __attribute__((ext_vector_type(8))) short bf16x8;
typedef __attribute__((ext_vector_type(4))) float f32x4;

__device__ __forceinline__ u16 f2bf(float x){
  u32 u = __float_as_uint(x);
  u32 r = (u + 0x7fffu + ((u>>16)&1u)) >> 16;
  return (u16)r;
}
__device__ __forceinline__ float bf2f(u32 b){ return __uint_as_float(b<<16); }
__device__ __forceinline__ u32 packbf(float a, float b){ return (u32)f2bf(a) | ((u32)f2bf(b)<<16); }

// DPP-accumulate; CTRL must be an immediate.
template<int CTRL>
__device__ __forceinline__ float dpp_add(float x){
  int y = __builtin_amdgcn_update_dpp(0, __float_as_int(x), CTRL, 0xF, 0xF, true);
  return x + __int_as_float(y);
}
// Reduction across each 16-lane row, result broadcast to all 16 lanes. Pure VALU.
__device__ __forceinline__ float red16(float x){
  x = dpp_add<0xB1>(x);   // quad_perm [1,0,3,2]  (xor 1)
  x = dpp_add<0x4E>(x);   // quad_perm [2,3,0,1]  (xor 2)
  x = dpp_add<0x124>(x);  // row_ror:4
  x = dpp_add<0x128>(x);  // row_ror:8
  return x;
}

// ---------------- fp32 -> bf16 elementwise ----------------
__global__ __launch_bounds__(256) void k_cvt(const float* __restrict__ in, u16* __restrict__ out, int n){
  int i = (blockIdx.x*256 + threadIdx.x)*8;
  if (i >= n) return;
  float4 a = *(const float4*)(in+i);
  float4 b = *(const float4*)(in+i+4);
  uint4 o;
  o.x = packbf(a.x,a.y); o.y = packbf(a.z,a.w);
  o.z = packbf(b.x,b.y); o.w = packbf(b.z,b.w);
  *(uint4*)(out+i) = o;
}

// ---------------- fp32 [R][C] -> bf16 transposed [C][R] ----------------
__global__ __launch_bounds__(256) void k_tcvt(const float* __restrict__ in, u16* __restrict__ out, int R, int C){
  __shared__ float tile[32][33];
  int c0 = blockIdx.x*32, r0 = blockIdx.y*32;
  int tx = threadIdx.x & 31, ty = threadIdx.x >> 5;
#pragma unroll
  for (int i=0;i<4;++i) tile[ty+8*i][tx] = in[(size_t)(r0+ty+8*i)*C + c0+tx];
  __syncthreads();
#pragma unroll
  for (int i=0;i<4;++i) out[(size_t)(c0+ty+8*i)*R + r0+tx] = f2bf(tile[tx][ty+8*i]);
}

// ---------------- ba = X @ W_ba  ->  eg = exp(g), beta ----------------
__global__ __launch_bounds__(256) void k_ba(const float* __restrict__ X, const float* __restrict__ W,
    const float* __restrict__ A_log, const float* __restrict__ dt_bias,
    float* __restrict__ eg, float* __restrict__ beta){
  int tid = threadIdx.x;
  int t = blockIdx.x*4 + (tid>>6);
  int j = tid & 63;
  const float* xr = X + (size_t)t*H_DIM;
  float acc = 0.f;
  for (int k=0;k<H_DIM;k+=4){
    float4 xv = *(const float4*)(xr+k);
    acc += xv.x*W[(size_t)(k+0)*64 + j];
    acc += xv.y*W[(size_t)(k+1)*64 + j];
    acc += xv.z*W[(size_t)(k+2)*64 + j];
    acc += xv.w*W[(size_t)(k+3)*64 + j];
  }
  if (j < HVn) {
    beta[t*HVn + j] = 1.f/(1.f+__expf(-acc));
  } else {
    int h = j - HVn;
    float x = acc + dt_bias[h];
    float sp = (x > 20.f) ? x : log1pf(__expf(x));
    eg[t*HVn + h] = __expf(-__expf(A_log[h]) * sp);   // exp(g) precomputed
  }
}

// ---------------- bf16 MFMA GEMM: C[M][N] = A[M][K] * BT[N][K]^T ----------------
typedef const __attribute__((address_space(1))) u32* gas_t;
typedef __attribute__((address_space(3))) u32* las_t;
__device__ __forceinline__ void gld16(const void* g, void* l){
  __builtin_amdgcn_global_load_lds((gas_t)g, (las_t)l, 16, 0, 0);
}

template<int WRITE_BF16>
__global__ __launch_bounds__(256) void k_gemm(const u16* __restrict__ A, const u16* __restrict__ BT,
                                              void* __restrict__ Cout, int M, int N, int K){
  __shared__ __align__(16) u16 As[128*32];
  __shared__ __align__(16) u16 Bs[128*32];
  int tid = threadIdx.x, lane = tid & 63, wave = tid >> 6;
  int wr = wave >> 1, wc = wave & 1;
  int m0 = blockIdx.x*128, n0 = blockIdx.y*128;
  int fr = lane & 15, fq = lane >> 4;
  f32x4 zero = {0.f,0.f,0.f,0.f};
  f32x4 acc[4][4];
#pragma unroll
  for (int m=0;m<4;++m)
#pragma unroll
    for (int n=0;n<4;++n) acc[m][n] = zero;

  for (int kt=0; kt<K; kt+=32){
#pragma unroll
    for (int it=0; it<2; ++it){
      int c = (it*4 + wave)*64 + lane;      // 0..511 chunk of 16B
      int row = c >> 2, kc = (c & 3) << 3;
      gld16(A  + (size_t)(m0+row)*K + kt + kc, (char*)As + (size_t)(it*4+wave)*1024);
      gld16(BT + (size_t)(n0+row)*K + kt + kc, (char*)Bs + (size_t)(it*4+wave)*1024);
    }
    __syncthreads();
    bf16x8 af[4], bff[4];
#pragma unroll
    for (int m=0;m<4;++m) af[m]  = *(const bf16x8*)(As + (wr*64 + m*16 + fr)*32 + fq*8);
#pragma unroll
    for (int n=0;n<4;++n) bff[n] = *(const bf16x8*)(Bs + (wc*64 + n*16 + fr)*32 + fq*8);
#pragma unroll
    for (int m=0;m<4;++m)
#pragma unroll
      for (int n=0;n<4;++n)
        acc[m][n] = __builtin_amdgcn_mfma_f32_16x16x32_bf16(af[m], bff[n], acc[m][n], 0,0,0);
    __syncthreads();
  }
#pragma unroll
  for (int m=0;m<4;++m)
#pragma unroll
    for (int n=0;n<4;++n){
      int row = m0 + wr*64 + m*16 + fq*4;
      int col = n0 + wc*64 + n*16 + fr;
#pragma unroll
      for (int r=0;r<4;++r){
        float v = acc[m][n][r];
        if (WRITE_BF16) ((u16*)Cout)[(size_t)(row+r)*N + col] = f2bf(v);
        else            ((float*)Cout)[(size_t)(row+r)*N + col] = v;
      }
    }
}

// ---------------- causal depthwise conv(KW=4) + SiLU + l2norm(q,k) -> bf16 ----------------
__global__ __launch_bounds__(256) void k_conv(const u16* __restrict__ qkvz, const float* __restrict__ cw,
    u16* __restrict__ qn, u16* __restrict__ kn, u16* __restrict__ vv){
  int t = blockIdx.x;
  int region = blockIdx.y;                 // 0:q 1:k 2,3:v
  int c = region*2048 + threadIdx.x*8;     // 8 channels per thread
  float wgt[8][4];
#pragma unroll
  for (int i=0;i<8;++i){
    float4 wv = *(const float4*)(cw + (size_t)(c+i)*4);
    wgt[i][0]=wv.x; wgt[i][1]=wv.y; wgt[i][2]=wv.z; wgt[i][3]=wv.w;
  }
  float y[8];
#pragma unroll
  for (int i=0;i<8;++i) y[i]=0.f;
#pragma unroll
  for (int j=0;j<4;++j){
    int tt = t + j - 3;
    if (tt < 0) continue;
    uint4 raw = *(const uint4*)(qkvz + (size_t)tt*QKVZ_N + c);
    float xv[8];
    xv[0]=bf2f(raw.x&0xffffu); xv[1]=bf2f(raw.x>>16);
    xv[2]=bf2f(raw.y&0xffffu); xv[3]=bf2f(raw.y>>16);
    xv[4]=bf2f(raw.z&0xffffu); xv[5]=bf2f(raw.z>>16);
    xv[6]=bf2f(raw.w&0xffffu); xv[7]=bf2f(raw.w>>16);
#pragma unroll
    for (int i=0;i<8;++i) y[i] += xv[i]*wgt[i][j];
  }
#pragma unroll
  for (int i=0;i<8;++i){ y[i] = y[i] / (1.f + __expf(-y[i])); }   // SiLU

  if (region <= 1){
    float ss = 0.f;
#pragma unroll
    for (int i=0;i<8;++i) ss += y[i]*y[i];
    ss += __shfl_xor(ss,1); ss += __shfl_xor(ss,2);
    ss += __shfl_xor(ss,4); ss += __shfl_xor(ss,8);   // 16 lanes = one 128-dim head
    float sc = 1.f/sqrtf(ss + 1e-6f);
    if (region==0) sc *= 0.08838834764831845f;        // DK^-0.5
#pragma unroll
    for (int i=0;i<8;++i) y[i]*=sc;
    u16* dst = (region==0 ? qn : kn) + (size_t)t*KEY_DIM + (c - region*2048);
    *(uint4*)dst = make_uint4(packbf(y[0],y[1]),packbf(y[2],y[3]),packbf(y[4],y[5]),packbf(y[6],y[7]));
  } else {
    u16* dst = vv + (size_t)t*VAL_DIM + (c - 4096);
    *(uint4*)dst = make_uint4(packbf(y[0],y[1]),packbf(y[2],y[3]),packbf(y[4],y[5]),packbf(y[6],y[7]));
  }
}

// ---------------- gated delta rule recurrence (v3) ----------------
// 4096 independent state columns (h, v). 16 lanes per column x 8 d-elems,
// 4 columns per wave, 1024 waves. Reductions are pure-DPP (no LDS) -> short chain.
__global__ __launch_bounds__(256) void k_recur(const u16* __restrict__ qn, const u16* __restrict__ kn,
   const u16* __restrict__ vv, const float* __restrict__ eg_arr, const float* __restrict__ beta,
   float* __restrict__ o){
  int lane = threadIdx.x & 63, wave = threadIdx.x >> 6;
  int gcol = blockIdx.x*16 + wave*4 + (lane >> 4);   // global column 0..4095
  int h  = gcol >> 7;                                 // value head
  int kh = h >> 1;                                    // GQA r=2
  int dl = (lane & 15) << 3;                          // 8 d-elems per lane

  const uint4* kp = (const uint4*)(kn + kh*DKn + dl); // 16B per lane, 16 lanes = full row
  const uint4* qp = (const uint4*)(qn + kh*DKn + dl);
  const u16*   vp = vv + gcol;
  const float* ep = eg_arr + h;
  const float* bp = beta + h;
  float*       op = o + gcol;

  int ko = 0, so = 0, go = 0, oo = 0;                 // 32-bit element offsets
  uint4 kf = kp[0], qf = qp[0];
  u16 vt_ = vp[0];
  float egf = ep[0], btf = bp[0];
  float S[8];
#pragma unroll
  for (int i=0;i<8;++i) S[i]=0.f;
  bool writer = ((lane & 15) == 0);

  for (int t=0; t<T_LEN; ++t){
    uint4 kc=kf, qc=qf; u32 vc=vt_; float eg=egf, bc=btf;
    int adv = (t < T_LEN-1) ? 1 : 0;
    ko += adv*(KEY_DIM/8);                            // uint4 units
    so += adv*VAL_DIM;
    go += adv*HVn;
    kf = kp[ko]; qf = qp[ko];
    vt_ = vp[so];
    egf = ep[go]; btf = bp[go];

    float kr[8], qr[8];
    kr[0]=__uint_as_float(kc.x<<16); kr[1]=__uint_as_float(kc.x&0xffff0000u);
    kr[2]=__uint_as_float(kc.y<<16); kr[3]=__uint_as_float(kc.y&0xffff0000u);
    kr[4]=__uint_as_float(kc.z<<16); kr[5]=__uint_as_float(kc.z&0xffff0000u);
    kr[6]=__uint_as_float(kc.w<<16); kr[7]=__uint_as_float(kc.w&0xffff0000u);
    qr[0]=__uint_as_float(qc.x<<16); qr[1]=__uint_as_float(qc.x&0xffff0000u);
    qr[2]=__uint_as_float(qc.y<<16); qr[3]=__uint_as_float(qc.y&0xffff0000u);
    qr[4]=__uint_as_float(qc.z<<16); qr[5]=__uint_as_float(qc.z&0xffff0000u);
    qr[6]=__uint_as_float(qc.w<<16); qr[7]=__uint_as_float(qc.w&0xffff0000u);

    float kv = kr[0]*S[0];
#pragma unroll
    for (int i=1;i<8;++i) kv = fmaf(kr[i], S[i], kv);
    kv = red16(kv);

    float delta = (bf2f(vc) - eg*kv)*bc;
#pragma unroll
    for (int i=0;i<8;++i) S[i] = fmaf(kr[i], delta, eg*S[i]);

    float ov = qr[0]*S[0];
#pragma unroll
    for (int i=1;i<8;++i) ov = fmaf(qr[i], S[i], ov);
    ov = red16(ov);
    if (writer) op[oo] = ov;
    oo += VAL_DIM;
  }
}

// ---------------- gated RMSNorm * silu(z) -> bf16 ----------------
__global__ __launch_bounds__(256) void k_gnorm(const float* __restrict__ o, const u16* __restrict__ qkvz,
    const float* __restrict__ nw, u16* __restrict__ og){
  int t = blockIdx.x;
  int base = threadIdx.x*16;               // 16 elems/thread, 8 threads per 128-dim head
  const float* src = o + (size_t)t*VAL_DIM + base;
  float x[16];
#pragma unroll
  for (int i=0;i<4;++i){
    float4 f = *(const float4*)(src + i*4);
    x[i*4+0]=f.x; x[i*4+1]=f.y; x[i*4+2]=f.z; x[i*4+3]=f.w;
  }
  float ss=0.f;
#pragma unroll
  for (int i=0;i<16;++i) ss += x[i]*x[i];
  ss += __shfl_xor(ss,1); ss += __shfl_xor(ss,2); ss += __shfl_xor(ss,4);
  float rs = 1.f/sqrtf(ss*(1.f/128.f) + 1e-6f);
  const u16* zp = qkvz + (size_t)t*QKVZ_N + 8192 + base;
  uint4 z0 = *(const uint4*)zp;
  uint4 z1 = *(const uint4*)(zp+8);
  u32 zr[8] = {z0.x,z0.y,z0.z,z0.w,z1.x,z1.y,z1.z,z1.w};
  u32 outw[8];
#pragma unroll
  for (int p=0;p<8;++p){
    float za = bf2f(zr[p]&0xffffu), zb = bf2f(zr[p]>>16);
    float sa = za/(1.f+__expf(-za)), sb = zb/(1.f+__expf(-zb));
    int i0 = p*2, i1 = p*2+1;
    float oa = x[i0]*rs*nw[(base+i0)&127]*sa;
    float ob = x[i1]*rs*nw[(base+i1)&127]*sb;
    outw[p] = packbf(oa, ob);
  }
  uint4* dst = (uint4*)(og + (size_t)t*VAL_DIM + base);
  dst[0] = make_uint4(outw[0],outw[1],outw[2],outw[3]);
  dst[1] = make_uint4(outw[4],outw[5],outw[6],outw[7]);
}

extern "C" void kernel_launch(void* const* d_in, const int* in_sizes, int n_in,
                              void* d_out, int out_size, void* d_ws, size_t ws_size,
                              hipStream_t stream) {
  const float* hidden  = (const float*)d_in[0];
  const float* W_qkvz  = (const float*)d_in[1];
  const float* W_ba    = (const float*)d_in[2];
  const float* conv_w  = (const float*)d_in[3];
  const float* A_log   = (const float*)d_in[4];
  const float* dt_bias = (const float*)d_in[5];
  const float* norm_w  = (const float*)d_in[6];
  const float* W_out   = (const float*)d_in[7];

  // workspace layout (253MB, with write-before-read aliasing):
  //   [0, 16.8M)      Xb   (bf16 hidden)        } aliased by O (fp32, 67.1M)
  //   [16.8M, 67.1M)  W1T  (bf16 W_qkvz^T)      }  after GEMM1
  //   [67.1M, 167.8M) QKVZ (bf16)
  //   [167.8M,184.5M) QN   (bf16)               } aliased by OG (bf16, 33.6M)
  //   [184.5M,201.3M) KN   (bf16)               }  after recurrence
  //   [201.3M,234.9M) V    (bf16)
  //   [234.9M,251.7M) WoT  (bf16 W_out^T)
  //   [251.7M,252.7M) EG, B (fp32)
  char* w = (char*)d_ws;
  size_t need = 252706816;
  if (ws_size < need) return;

  u16*   Xb   = (u16*)(w + 0);
  u16*   W1T  = (u16*)(w + 16777216);
  u16*   QKVZ = (u16*)(w + 67108864);
  u16*   QN   = (u16*)(w + 167772160);
  u16*   KN   = (u16*)(w + 184549376);
  u16*   V    = (u16*)(w + 201326592);
  u16*   WoT  = (u16*)(w + 234881024);
  float* EG   = (float*)(w + 251658240);
  float* B    = (float*)(w + 252182528);
  float* O    = (float*)(w + 0);           // alias Xb+W1T (dead after GEMM1)
  u16*   OG   = (u16*)(w + 167772160);     // alias QN+KN (dead after recurrence)

  k_cvt<<<4096,256,0,stream>>>(hidden, Xb, T_LEN*H_DIM);
  k_tcvt<<<dim3(QKVZ_N/32, H_DIM/32),256,0,stream>>>(W_qkvz, W1T, H_DIM, QKVZ_N);
  k_tcvt<<<dim3(H_DIM/32, VAL_DIM/32),256,0,stream>>>(W_out, WoT, VAL_DIM, H_DIM);
  k_ba<<<T_LEN/4,256,0,stream>>>(hidden, W_ba, A_log, dt_bias, EG, B);
  k_gemm<1><<<dim3(T_LEN/128, QKVZ_N/128),256,0,stream>>>(Xb, W1T, QKVZ, T_LEN, QKVZ_N, H_DIM);
  k_conv<<<dim3(T_LEN,4),256,0,stream>>>(QKVZ, conv_w, QN, KN, V);
  k_recur<<<256,256,0,stream>>>(QN, KN, V, EG, B, O);
  k_gnorm<<<T_LEN,256,0,stream>>>(O, QKVZ, norm_w, OG);
  k_gemm<0><<<dim3(T_LEN/128, H_DIM/128),256,0,stream>>>(OG, WoT, d_out, T_LEN, H_DIM, VAL_DIM);
}

// Round 6
// 1557.042 us; speedup vs baseline: 1.9675x; 1.4814x over previous
//
#include <hip/hip_runtime.h>
#include <hip/hip_bf16.h>

#define T_LEN 4096
#define H_DIM 2048
#define HKn 16
#define HVn 32
#define DKn 128
#define DVn 128
#define KEY_DIM 2048
#define VAL_DIM 4096
#define QKVZ_N 12288
#define CHUNK 32

typedef unsigned int u32;
typedef unsigned short u16;
typedef __attribute__((ext_vector_type(8))) short bf16x8;
typedef __attribute__((ext_vector_type(4))) float f32x4;

__device__ __forceinline__ u16 f2bf(float x){
  u32 u = __float_as_uint(x);
  u32 r = (u + 0x7fffu + ((u>>16)&1u)) >> 16;
  return (u16)r;
}
__device__ __forceinline__ float bf2f(u32 b){ return __uint_as_float(b<<16); }
__device__ __forceinline__ u32 packbf(float a, float b){ return (u32)f2bf(a) | ((u32)f2bf(b)<<16); }

// DPP-accumulate; CTRL must be an immediate.
template<int CTRL>
__device__ __forceinline__ float dpp_add(float x){
  int y = __builtin_amdgcn_update_dpp(0, __float_as_int(x), CTRL, 0xF, 0xF, true);
  return x + __int_as_float(y);
}
// Reduction across each 16-lane row, result broadcast to all 16 lanes. Pure VALU.
__device__ __forceinline__ float red16(float x){
  x = dpp_add<0xB1>(x);   // quad_perm [1,0,3,2]  (xor 1)
  x = dpp_add<0x4E>(x);   // quad_perm [2,3,0,1]  (xor 2)
  x = dpp_add<0x124>(x);  // row_ror:4
  x = dpp_add<0x128>(x);  // row_ror:8
  return x;
}

// ---------------- fp32 -> bf16 elementwise ----------------
__global__ __launch_bounds__(256) void k_cvt(const float* __restrict__ in, u16* __restrict__ out, int n){
  int i = (blockIdx.x*256 + threadIdx.x)*8;
  if (i >= n) return;
  float4 a = *(const float4*)(in+i);
  float4 b = *(const float4*)(in+i+4);
  uint4 o;
  o.x = packbf(a.x,a.y); o.y = packbf(a.z,a.w);
  o.z = packbf(b.x,b.y); o.w = packbf(b.z,b.w);
  *(uint4*)(out+i) = o;
}

// ---------------- fp32 [R][C] -> bf16 transposed [C][R] ----------------
__global__ __launch_bounds__(256) void k_tcvt(const float* __restrict__ in, u16* __restrict__ out, int R, int C){
  __shared__ float tile[32][33];
  int c0 = blockIdx.x*32, r0 = blockIdx.y*32;
  int tx = threadIdx.x & 31, ty = threadIdx.x >> 5;
#pragma unroll
  for (int i=0;i<4;++i) tile[ty+8*i][tx] = in[(size_t)(r0+ty+8*i)*C + c0+tx];
  __syncthreads();
#pragma unroll
  for (int i=0;i<4;++i) out[(size_t)(c0+ty+8*i)*R + r0+tx] = f2bf(tile[tx][ty+8*i]);
}

// ---------------- ba = X @ W_ba  ->  eg = exp(g), beta ----------------
__global__ __launch_bounds__(256) void k_ba(const float* __restrict__ X, const float* __restrict__ W,
    const float* __restrict__ A_log, const float* __restrict__ dt_bias,
    float* __restrict__ eg, float* __restrict__ beta){
  int tid = threadIdx.x;
  int t = blockIdx.x*4 + (tid>>6);
  int j = tid & 63;
  const float* xr = X + (size_t)t*H_DIM;
  float acc = 0.f;
  for (int k=0;k<H_DIM;k+=4){
    float4 xv = *(const float4*)(xr+k);
    acc += xv.x*W[(size_t)(k+0)*64 + j];
    acc += xv.y*W[(size_t)(k+1)*64 + j];
    acc += xv.z*W[(size_t)(k+2)*64 + j];
    acc += xv.w*W[(size_t)(k+3)*64 + j];
  }
  if (j < HVn) {
    beta[t*HVn + j] = 1.f/(1.f+__expf(-acc));
  } else {
    int h = j - HVn;
    float x = acc + dt_bias[h];
    float sp = (x > 20.f) ? x : log1pf(__expf(x));
    eg[t*HVn + h] = __expf(-__expf(A_log[h]) * sp);   // exp(g) precomputed
  }
}

// ---------------- bf16 MFMA GEMM: C[M][N] = A[M][K] * BT[N][K]^T ----------------
typedef const __attribute__((address_space(1))) u32* gas_t;
typedef __attribute__((address_space(3))) u32* las_t;
__device__ __forceinline__ void gld16(const void* g, void* l){
  __builtin_amdgcn_global_load_lds((gas_t)g, (las_t)l, 16, 0, 0);
}
__device__ __forceinline__ void gld4(const void* g, void* l){
  __builtin_amdgcn_global_load_lds((gas_t)g, (las_t)l, 4, 0, 0);
}

template<int WRITE_BF16>
__global__ __launch_bounds__(256) void k_gemm(const u16* __restrict__ A, const u16* __restrict__ BT,
                                              void* __restrict__ Cout, int M, int N, int K){
  __shared__ __align__(16) u16 As[128*32];
  __shared__ __align__(16) u16 Bs[128*32];
  int tid = threadIdx.x, lane = tid & 63, wave = tid >> 6;
  int wr = wave >> 1, wc = wave & 1;
  int m0 = blockIdx.x*128, n0 = blockIdx.y*128;
  int fr = lane & 15, fq = lane >> 4;
  f32x4 zero = {0.f,0.f,0.f,0.f};
  f32x4 acc[4][4];
#pragma unroll
  for (int m=0;m<4;++m)
#pragma unroll
    for (int n=0;n<4;++n) acc[m][n] = zero;

  for (int kt=0; kt<K; kt+=32){
#pragma unroll
    for (int it=0; it<2; ++it){
      int c = (it*4 + wave)*64 + lane;      // 0..511 chunk of 16B
      int row = c >> 2, kc = (c & 3) << 3;
      gld16(A  + (size_t)(m0+row)*K + kt + kc, (char*)As + (size_t)(it*4+wave)*1024);
      gld16(BT + (size_t)(n0+row)*K + kt + kc, (char*)Bs + (size_t)(it*4+wave)*1024);
    }
    __syncthreads();
    bf16x8 af[4], bff[4];
#pragma unroll
    for (int m=0;m<4;++m) af[m]  = *(const bf16x8*)(As + (wr*64 + m*16 + fr)*32 + fq*8);
#pragma unroll
    for (int n=0;n<4;++n) bff[n] = *(const bf16x8*)(Bs + (wc*64 + n*16 + fr)*32 + fq*8);
#pragma unroll
    for (int m=0;m<4;++m)
#pragma unroll
      for (int n=0;n<4;++n)
        acc[m][n] = __builtin_amdgcn_mfma_f32_16x16x32_bf16(af[m], bff[n], acc[m][n], 0,0,0);
    __syncthreads();
  }
#pragma unroll
  for (int m=0;m<4;++m)
#pragma unroll
    for (int n=0;n<4;++n){
      int row = m0 + wr*64 + m*16 + fq*4;
      int col = n0 + wc*64 + n*16 + fr;
#pragma unroll
      for (int r=0;r<4;++r){
        float v = acc[m][n][r];
        if (WRITE_BF16) ((u16*)Cout)[(size_t)(row+r)*N + col] = f2bf(v);
        else            ((float*)Cout)[(size_t)(row+r)*N + col] = v;
      }
    }
}

// ---------------- causal depthwise conv(KW=4) + SiLU + l2norm(q,k) -> bf16 ----------------
__global__ __launch_bounds__(256) void k_conv(const u16* __restrict__ qkvz, const float* __restrict__ cw,
    u16* __restrict__ qn, u16* __restrict__ kn, u16* __restrict__ vv){
  int t = blockIdx.x;
  int region = blockIdx.y;                 // 0:q 1:k 2,3:v
  int c = region*2048 + threadIdx.x*8;     // 8 channels per thread
  float wgt[8][4];
#pragma unroll
  for (int i=0;i<8;++i){
    float4 wv = *(const float4*)(cw + (size_t)(c+i)*4);
    wgt[i][0]=wv.x; wgt[i][1]=wv.y; wgt[i][2]=wv.z; wgt[i][3]=wv.w;
  }
  float y[8];
#pragma unroll
  for (int i=0;i<8;++i) y[i]=0.f;
#pragma unroll
  for (int j=0;j<4;++j){
    int tt = t + j - 3;
    if (tt < 0) continue;
    uint4 raw = *(const uint4*)(qkvz + (size_t)tt*QKVZ_N + c);
    float xv[8];
    xv[0]=bf2f(raw.x&0xffffu); xv[1]=bf2f(raw.x>>16);
    xv[2]=bf2f(raw.y&0xffffu); xv[3]=bf2f(raw.y>>16);
    xv[4]=bf2f(raw.z&0xffffu); xv[5]=bf2f(raw.z>>16);
    xv[6]=bf2f(raw.w&0xffffu); xv[7]=bf2f(raw.w>>16);
#pragma unroll
    for (int i=0;i<8;++i) y[i] += xv[i]*wgt[i][j];
  }
#pragma unroll
  for (int i=0;i<8;++i){ y[i] = y[i] / (1.f + __expf(-y[i])); }   // SiLU

  if (region <= 1){
    float ss = 0.f;
#pragma unroll
    for (int i=0;i<8;++i) ss += y[i]*y[i];
    ss += __shfl_xor(ss,1); ss += __shfl_xor(ss,2);
    ss += __shfl_xor(ss,4); ss += __shfl_xor(ss,8);   // 16 lanes = one 128-dim head
    float sc = 1.f/sqrtf(ss + 1e-6f);
    if (region==0) sc *= 0.08838834764831845f;        // DK^-0.5
#pragma unroll
    for (int i=0;i<8;++i) y[i]*=sc;
    u16* dst = (region==0 ? qn : kn) + (size_t)t*KEY_DIM + (c - region*2048);
    *(uint4*)dst = make_uint4(packbf(y[0],y[1]),packbf(y[2],y[3]),packbf(y[4],y[5]),packbf(y[6],y[7]));
  } else {
    u16* dst = vv + (size_t)t*VAL_DIM + (c - 4096);
    *(uint4*)dst = make_uint4(packbf(y[0],y[1]),packbf(y[2],y[3]),packbf(y[4],y[5]),packbf(y[6],y[7]));
  }
}

// ---------------- gated delta rule recurrence (v4: LDS chunk staging) ----------------
// 4096 independent state columns. Block = 256 threads = 16 columns of ONE head
// (so all waves share the same K/Q rows). 16 lanes per column x 8 d-elems.
// K/Q/V/eg/beta staged per 32-step chunk into LDS via global_load_lds, double-buffered.
__global__ __launch_bounds__(256) void k_recur(const u16* __restrict__ qn, const u16* __restrict__ kn,
   const u16* __restrict__ vv, const float* __restrict__ eg_arr, const float* __restrict__ beta,
   float* __restrict__ o){
  __shared__ __align__(16) u16 Ks[2][CHUNK][DKn];   // 16KB
  __shared__ __align__(16) u16 Qs[2][CHUNK][DKn];   // 16KB
  __shared__ __align__(16) u16 Vs[2][CHUNK][16];    // 2KB
  __shared__ __align__(16) float EGs[2][64];        // 512B (32 used + 32 pad)
  __shared__ __align__(16) float Bs2[2][64];        // 512B

  int tid = threadIdx.x, lane = tid & 63, wave = tid >> 6;
  int gcol0 = blockIdx.x * 16;
  int h  = gcol0 >> 7;
  int kh = h >> 1;                                  // GQA r=2
  int col_local = wave*4 + (lane >> 4);             // 0..15
  int gcol = gcol0 + col_local;
  int dl = (lane & 15) << 3;                        // 8 d-elems per lane

  // staging geometry
  int lrow  = wave*4 + (lane >> 4);                 // row within 16-row round
  int lcol8 = (lane & 15) << 3;                     // u16 offset within 256B row

  const u16* kbase0 = kn + (size_t)kh*DKn;
  const u16* qbase0 = qn + (size_t)kh*DKn;

  auto stage = [&](int c, int b){
    const u16* kb = kbase0 + (size_t)(c*CHUNK)*KEY_DIM;
    const u16* qb = qbase0 + (size_t)(c*CHUNK)*KEY_DIM;
#pragma unroll
    for (int r=0;r<2;++r){
      gld16(kb + (size_t)(r*16 + lrow)*KEY_DIM + lcol8, (char*)&Ks[b][0][0] + r*4096 + wave*1024);
      gld16(qb + (size_t)(r*16 + lrow)*KEY_DIM + lcol8, (char*)&Qs[b][0][0] + r*4096 + wave*1024);
    }
    if (wave == 0){      // V: 32 t x 32B = 1KB = 64 lanes x 16B
      gld16(vv + (size_t)(c*CHUNK + (lane>>1))*VAL_DIM + gcol0 + (lane&1)*8,
            (char*)&Vs[b][0][0]);
    } else if (wave == 1){
      gld4(eg_arr + (size_t)(c*CHUNK + (lane&31))*HVn + h, (char*)&EGs[b][0]);
    } else if (wave == 2){
      gld4(beta   + (size_t)(c*CHUNK + (lane&31))*HVn + h, (char*)&Bs2[b][0]);
    }
  };

  float S[8];
#pragma unroll
  for (int i=0;i<8;++i) S[i]=0.f;
  bool writer = ((lane & 15) == 0);
  float* op = o + gcol;
  int oo = 0;

  stage(0, 0);
  const int NC = T_LEN/CHUNK;
  for (int c=0; c<NC; ++c){
    int b = c & 1;
    __syncthreads();                       // stage(c) complete; buf b safe
    if (c+1 < NC) stage(c+1, b^1);

    uint4 kf = *(const uint4*)&Ks[b][0][dl];
    uint4 qf = *(const uint4*)&Qs[b][0][dl];
    u16 vf = Vs[b][0][col_local];
    float egf = EGs[b][0], btf = Bs2[b][0];

#pragma unroll 4
    for (int tt=0; tt<CHUNK; ++tt){
      uint4 kc=kf, qc=qf; u32 vc=vf; float eg=egf, bc=btf;
      int tn = (tt+1 < CHUNK) ? tt+1 : tt;
      kf = *(const uint4*)&Ks[b][tn][dl];
      qf = *(const uint4*)&Qs[b][tn][dl];
      vf = Vs[b][tn][col_local];
      egf = EGs[b][tn]; btf = Bs2[b][tn];

      float kr[8], qr[8];
      kr[0]=__uint_as_float(kc.x<<16); kr[1]=__uint_as_float(kc.x&0xffff0000u);
      kr[2]=__uint_as_float(kc.y<<16); kr[3]=__uint_as_float(kc.y&0xffff0000u);
      kr[4]=__uint_as_float(kc.z<<16); kr[5]=__uint_as_float(kc.z&0xffff0000u);
      kr[6]=__uint_as_float(kc.w<<16); kr[7]=__uint_as_float(kc.w&0xffff0000u);
      qr[0]=__uint_as_float(qc.x<<16); qr[1]=__uint_as_float(qc.x&0xffff0000u);
      qr[2]=__uint_as_float(qc.y<<16); qr[3]=__uint_as_float(qc.y&0xffff0000u);
      qr[4]=__uint_as_float(qc.z<<16); qr[5]=__uint_as_float(qc.z&0xffff0000u);
      qr[6]=__uint_as_float(qc.w<<16); qr[7]=__uint_as_float(qc.w&0xffff0000u);

      // kv dot, tree form (short chain)
      float a0 = fmaf(kr[1],S[1], kr[0]*S[0]);
      float a1 = fmaf(kr[3],S[3], kr[2]*S[2]);
      float a2 = fmaf(kr[5],S[5], kr[4]*S[4]);
      float a3 = fmaf(kr[7],S[7], kr[6]*S[6]);
      float kv = red16((a0+a1)+(a2+a3));

      float delta = (bf2f(vc) - eg*kv)*bc;
#pragma unroll
      for (int i=0;i<8;++i) S[i] = fmaf(kr[i], delta, eg*S[i]);

      float b0 = fmaf(qr[1],S[1], qr[0]*S[0]);
      float b1 = fmaf(qr[3],S[3], qr[2]*S[2]);
      float b2 = fmaf(qr[5],S[5], qr[4]*S[4]);
      float b3 = fmaf(qr[7],S[7], qr[6]*S[6]);
      float ov = red16((b0+b1)+(b2+b3));
      if (writer) op[oo] = ov;
      oo += VAL_DIM;
    }
  }
}

// ---------------- gated RMSNorm * silu(z) -> bf16 ----------------
__global__ __launch_bounds__(256) void k_gnorm(const float* __restrict__ o, const u16* __restrict__ qkvz,
    const float* __restrict__ nw, u16* __restrict__ og){
  int t = blockIdx.x;
  int base = threadIdx.x*16;               // 16 elems/thread, 8 threads per 128-dim head
  const float* src = o + (size_t)t*VAL_DIM + base;
  float x[16];
#pragma unroll
  for (int i=0;i<4;++i){
    float4 f = *(const float4*)(src + i*4);
    x[i*4+0]=f.x; x[i*4+1]=f.y; x[i*4+2]=f.z; x[i*4+3]=f.w;
  }
  float ss=0.f;
#pragma unroll
  for (int i=0;i<16;++i) ss += x[i]*x[i];
  ss += __shfl_xor(ss,1); ss += __shfl_xor(ss,2); ss += __shfl_xor(ss,4);
  float rs = 1.f/sqrtf(ss*(1.f/128.f) + 1e-6f);
  const u16* zp = qkvz + (size_t)t*QKVZ_N + 8192 + base;
  uint4 z0 = *(const uint4*)zp;
  uint4 z1 = *(const uint4*)(zp+8);
  u32 zr[8] = {z0.x,z0.y,z0.z,z0.w,z1.x,z1.y,z1.z,z1.w};
  u32 outw[8];
#pragma unroll
  for (int p=0;p<8;++p){
    float za = bf2f(zr[p]&0xffffu), zb = bf2f(zr[p]>>16);
    float sa = za/(1.f+__expf(-za)), sb = zb/(1.f+__expf(-zb));
    int i0 = p*2, i1 = p*2+1;
    float oa = x[i0]*rs*nw[(base+i0)&127]*sa;
    float ob = x[i1]*rs*nw[(base+i1)&127]*sb;
    outw[p] = packbf(oa, ob);
  }
  uint4* dst = (uint4*)(og + (size_t)t*VAL_DIM + base);
  dst[0] = make_uint4(outw[0],outw[1],outw[2],outw[3]);
  dst[1] = make_uint4(outw[4],outw[5],outw[6],outw[7]);
}

extern "C" void kernel_launch(void* const* d_in, const int* in_sizes, int n_in,
                              void* d_out, int out_size, void* d_ws, size_t ws_size,
                              hipStream_t stream) {
  const float* hidden  = (const float*)d_in[0];
  const float* W_qkvz  = (const float*)d_in[1];
  const float* W_ba    = (const float*)d_in[2];
  const float* conv_w  = (const float*)d_in[3];
  const float* A_log   = (const float*)d_in[4];
  const float* dt_bias = (const float*)d_in[5];
  const float* norm_w  = (const float*)d_in[6];
  const float* W_out   = (const float*)d_in[7];

  // workspace layout (253MB, with write-before-read aliasing):
  //   [0, 16.8M)      Xb   (bf16 hidden)        } aliased by O (fp32, 67.1M)
  //   [16.8M, 67.1M)  W1T  (bf16 W_qkvz^T)      }  after GEMM1
  //   [67.1M, 167.8M) QKVZ (bf16)
  //   [167.8M,184.5M) QN   (bf16)               } aliased by OG (bf16, 33.6M)
  //   [184.5M,201.3M) KN   (bf16)               }  after recurrence
  //   [201.3M,234.9M) V    (bf16)
  //   [234.9M,251.7M) WoT  (bf16 W_out^T)
  //   [251.7M,252.7M) EG, B (fp32)
  char* w = (char*)d_ws;
  size_t need = 252706816;
  if (ws_size < need) return;

  u16*   Xb   = (u16*)(w + 0);
  u16*   W1T  = (u16*)(w + 16777216);
  u16*   QKVZ = (u16*)(w + 67108864);
  u16*   QN   = (u16*)(w + 167772160);
  u16*   KN   = (u16*)(w + 184549376);
  u16*   V    = (u16*)(w + 201326592);
  u16*   WoT  = (u16*)(w + 234881024);
  float* EG   = (float*)(w + 251658240);
  float* B    = (float*)(w + 252182528);
  float* O    = (float*)(w + 0);           // alias Xb+W1T (dead after GEMM1)
  u16*   OG   = (u16*)(w + 167772160);     // alias QN+KN (dead after recurrence)

  k_cvt<<<4096,256,0,stream>>>(hidden, Xb, T_LEN*H_DIM);
  k_tcvt<<<dim3(QKVZ_N/32, H_DIM/32),256,0,stream>>>(W_qkvz, W1T, H_DIM, QKVZ_N);
  k_tcvt<<<dim3(H_DIM/32, VAL_DIM/32),256,0,stream>>>(W_out, WoT, VAL_DIM, H_DIM);
  k_ba<<<T_LEN/4,256,0,stream>>>(hidden, W_ba, A_log, dt_bias, EG, B);
  k_gemm<1><<<dim3(T_LEN/128, QKVZ_N/128),256,0,stream>>>(Xb, W1T, QKVZ, T_LEN, QKVZ_N, H_DIM);
  k_conv<<<dim3(T_LEN,4),256,0,stream>>>(QKVZ, conv_w, QN, KN, V);
  k_recur<<<256,256,0,stream>>>(QN, KN, V, EG, B, O);
  k_gnorm<<<T_LEN,256,0,stream>>>(O, QKVZ, norm_w, OG);
  k_gemm<0><<<dim3(T_LEN/128, H_DIM/128),256,0,stream>>>(OG, WoT, d_out, T_LEN, H_DIM, VAL_DIM);
}